// Round 1
// baseline (9751.554 us; speedup 1.0000x reference)
//
#include <hip/hip_runtime.h>
#include <hip/hip_bf16.h>
#include <math.h>

#define Bb   4
#define Tt   1024
#define Cc   768
#define Hh   12
#define Dd   64
#define Ll   12
#define Vv   10000
#define TEe  64
#define WTEe 704
#define MTOT 4096   // B*T

typedef __bf16 bf16x8 __attribute__((ext_vector_type(8)));
typedef float  f32x4  __attribute__((ext_vector_type(4)));

__device__ inline unsigned short f2bf(float f) {
    unsigned int u = __float_as_uint(f);
    unsigned int r = (u + 0x7fffu + ((u >> 16) & 1u)) >> 16;   // RNE
    return (unsigned short)r;
}
__device__ inline uint4 pack8(float4 a, float4 b) {
    uint4 o;
    o.x = (unsigned)f2bf(a.x) | ((unsigned)f2bf(a.y) << 16);
    o.y = (unsigned)f2bf(a.z) | ((unsigned)f2bf(a.w) << 16);
    o.z = (unsigned)f2bf(b.x) | ((unsigned)f2bf(b.y) << 16);
    o.w = (unsigned)f2bf(b.z) | ((unsigned)f2bf(b.w) << 16);
    return o;
}

// ---------------------------------------------------------------------------
// Embedding: x[b,t,c] = concat(wte[idx], cos(ts*freq+phase)) + wpe[t]
// ---------------------------------------------------------------------------
__global__ __launch_bounds__(256)
void embed_kernel(const int* __restrict__ idx, const float* __restrict__ ts,
                  const float* __restrict__ wte, const float* __restrict__ freq,
                  const float* __restrict__ ph, const float* __restrict__ wpe,
                  float* __restrict__ x)
{
    const int bt  = blockIdx.x;
    const int t   = bt & (Tt - 1);
    const int tok = idx[bt];
    const float tv = ts[bt];
#pragma unroll
    for (int j = 0; j < 3; ++j) {
        int c = threadIdx.x + (j << 8);
        float val;
        if (c < WTEe) {
            val = wte[(size_t)tok * WTEe + c];
        } else {
            int e = c - WTEe;
            val = cosf(tv * freq[e] + ph[e]);
        }
        x[(size_t)bt * Cc + c] = val + wpe[(size_t)t * Cc + c];
    }
}

// ---------------------------------------------------------------------------
// LayerNorm: one row (768) per block of 256 threads
// ---------------------------------------------------------------------------
__global__ __launch_bounds__(256)
void ln_kernel(const float* __restrict__ x, const float* __restrict__ wt,
               const float* __restrict__ bs, float* __restrict__ out)
{
    const int row = blockIdx.x;
    const int tid = threadIdx.x;
    const float* xr = x + (size_t)row * Cc;
    float v0 = xr[tid], v1 = xr[tid + 256], v2 = xr[tid + 512];
    float s = v0 + v1 + v2;
#pragma unroll
    for (int m = 32; m; m >>= 1) s += __shfl_xor(s, m);
    __shared__ float red[4];
    const int wv = tid >> 6;
    if ((tid & 63) == 0) red[wv] = s;
    __syncthreads();
    float mu = (red[0] + red[1] + red[2] + red[3]) * (1.f / 768.f);
    float d0 = v0 - mu, d1 = v1 - mu, d2 = v2 - mu;
    float s2 = d0 * d0 + d1 * d1 + d2 * d2;
#pragma unroll
    for (int m = 32; m; m >>= 1) s2 += __shfl_xor(s2, m);
    __syncthreads();
    if ((tid & 63) == 0) red[wv] = s2;
    __syncthreads();
    float var = (red[0] + red[1] + red[2] + red[3]) * (1.f / 768.f);
    float rs = rsqrtf(var + 1e-5f);
    float* orow = out + (size_t)row * Cc;
    orow[tid]       = d0 * rs * wt[tid]       + bs[tid];
    orow[tid + 256] = d1 * rs * wt[tid + 256] + bs[tid + 256];
    orow[tid + 512] = d2 * rs * wt[tid + 512] + bs[tid + 512];
}

// ---------------------------------------------------------------------------
// GEMM: out[M,N] = A[M,K] @ W[N,K]^T (+bias) (+epilogue)
// f32 inputs, bf16 conversion during LDS staging, MFMA 16x16x32 bf16.
// BM=BN=64, BK=32, 256 threads = 4 waves, each wave a 32x32 quadrant.
// LDS is fragment-major: frag reads are ds_read_b128 at lane*16 (conflict-free).
// EPI: 0 = bias only, 1 = bias + resid add, 2 = bias + exact GELU
// ---------------------------------------------------------------------------
template<int EPI>
__global__ __launch_bounds__(256)
void gemm_bt(const float* __restrict__ A, const float* __restrict__ W,
             const float* __restrict__ bias, const float* __restrict__ resid,
             float* __restrict__ out, int N, int K)
{
    __shared__ uint4 AsF[4][64];
    __shared__ uint4 BsF[4][64];
    const int tid  = threadIdx.x;
    const int lane = tid & 63;
    const int w    = tid >> 6;
    const int wr   = w >> 1, wc = w & 1;
    const int m0   = blockIdx.x * 64, n0 = blockIdx.y * 64;
    const int r    = tid >> 2, g = tid & 3;
    const int mt   = r >> 4;
    const int dl   = (r & 15) | (g << 4);

    const float* ap = A + (size_t)(m0 + r) * K + g * 8;
    const int brow  = n0 + r;
    const float* bp = W + (size_t)brow * K + g * 8;
    const bool bvalid = brow < N;

    f32x4 acc[2][2] = {};

    for (int k0 = 0; k0 < K; k0 += 32) {
        float4 a0 = *(const float4*)(ap + k0);
        float4 a1 = *(const float4*)(ap + k0 + 4);
        float4 b0 = make_float4(0.f, 0.f, 0.f, 0.f), b1 = b0;
        if (bvalid) {
            b0 = *(const float4*)(bp + k0);
            b1 = *(const float4*)(bp + k0 + 4);
        }
        __syncthreads();                 // prev-iter frag reads done
        AsF[mt][dl] = pack8(a0, a1);
        BsF[mt][dl] = pack8(b0, b1);
        __syncthreads();

        uint4 au0 = AsF[2 * wr][lane];
        uint4 au1 = AsF[2 * wr + 1][lane];
        uint4 bu0 = BsF[2 * wc][lane];
        uint4 bu1 = BsF[2 * wc + 1][lane];
        bf16x8 a_0 = __builtin_bit_cast(bf16x8, au0);
        bf16x8 a_1 = __builtin_bit_cast(bf16x8, au1);
        bf16x8 b_0 = __builtin_bit_cast(bf16x8, bu0);
        bf16x8 b_1 = __builtin_bit_cast(bf16x8, bu1);
        acc[0][0] = __builtin_amdgcn_mfma_f32_16x16x32_bf16(a_0, b_0, acc[0][0], 0, 0, 0);
        acc[0][1] = __builtin_amdgcn_mfma_f32_16x16x32_bf16(a_0, b_1, acc[0][1], 0, 0, 0);
        acc[1][0] = __builtin_amdgcn_mfma_f32_16x16x32_bf16(a_1, b_0, acc[1][0], 0, 0, 0);
        acc[1][1] = __builtin_amdgcn_mfma_f32_16x16x32_bf16(a_1, b_1, acc[1][1], 0, 0, 0);
    }

#pragma unroll
    for (int mi = 0; mi < 2; ++mi)
#pragma unroll
        for (int ni = 0; ni < 2; ++ni) {
            int col = n0 + wc * 32 + ni * 16 + (lane & 15);
            if (col >= N) continue;
            int rbase = m0 + wr * 32 + mi * 16 + ((lane >> 4) << 2);
            float bv = bias ? bias[col] : 0.f;
#pragma unroll
            for (int q = 0; q < 4; ++q) {
                float v = acc[mi][ni][q] + bv;
                size_t o = (size_t)(rbase + q) * N + col;
                if (EPI == 1) v += resid[o];
                if (EPI == 2) v = 0.5f * v * (1.f + erff(v * 0.70710678118f));
                out[o] = v;
            }
        }
}

// ---------------------------------------------------------------------------
// Fused causal attention, f32, online softmax.
// Block: 256 thr = 4 waves; wave w handles query row t0+w of head (b,h).
// K/V chunks of 64 keys staged in LDS; lane = key in phase A, lane = dim in B.
// ---------------------------------------------------------------------------
__global__ __launch_bounds__(256)
void attn_kernel(const float* __restrict__ qkv, float* __restrict__ y)
{
    __shared__ float Ks[64][68];
    __shared__ float Vs[64][68];
    __shared__ float qs[4][64];
    __shared__ float ps[4][64];
    const int tid  = threadIdx.x;
    const int lane = tid & 63;
    const int w    = tid >> 6;
    const int t0   = blockIdx.x * 4;
    const int bh   = blockIdx.y;
    const int b    = bh / Hh, h = bh % Hh;
    const int t    = t0 + w;
    const float scale = 0.125f;   // 1/sqrt(64)

    const size_t rowstride = 3 * Cc;
    const float* qrow  = qkv + ((size_t)(b * Tt + t)) * rowstride + h * Dd;
    qs[w][lane] = qrow[lane] * scale;
    const int kr  = tid >> 2;
    const int seg = (tid & 3) * 16;
    const float* kbase = qkv + (size_t)(b * Tt) * rowstride + Cc     + h * Dd;
    const float* vbase = qkv + (size_t)(b * Tt) * rowstride + 2 * Cc + h * Dd;

    float o = 0.f, mrun = -1e30f, lrun = 0.f;
    const int nch = t0 / 64 + 1;
    __syncthreads();

    for (int c = 0; c < nch; ++c) {
        const int s0 = c * 64;
        const float* kp = kbase + (size_t)(s0 + kr) * rowstride + seg;
        const float* vp = vbase + (size_t)(s0 + kr) * rowstride + seg;
#pragma unroll
        for (int u = 0; u < 4; ++u) {
            *(float4*)&Ks[kr][seg + 4 * u] = *(const float4*)(kp + 4 * u);
            *(float4*)&Vs[kr][seg + 4 * u] = *(const float4*)(vp + 4 * u);
        }
        __syncthreads();

        // phase A: lane = key s0+lane
        float sc = 0.f;
#pragma unroll
        for (int d = 0; d < 64; d += 4) {
            float4 kq = *(const float4*)&Ks[lane][d];
            float4 qq = *(const float4*)&qs[w][d];
            sc += qq.x * kq.x + qq.y * kq.y + qq.z * kq.z + qq.w * kq.w;
        }
        if (s0 + lane > t) sc = -1e30f;
        float cm = sc;
#pragma unroll
        for (int m = 32; m; m >>= 1) cm = fmaxf(cm, __shfl_xor(cm, m));
        float mnew = fmaxf(mrun, cm);
        float fac  = __expf(mrun - mnew);
        float p    = __expf(sc - mnew);
        float psum = p;
#pragma unroll
        for (int m = 32; m; m >>= 1) psum += __shfl_xor(psum, m);
        lrun = lrun * fac + psum;
        mrun = mnew;
        ps[w][lane] = p;
        o *= fac;
        __syncthreads();

        // phase B: lane = dim
#pragma unroll
        for (int l4 = 0; l4 < 64; l4 += 4) {
            float4 pq = *(const float4*)&ps[w][l4];
            o += pq.x * Vs[l4][lane] + pq.y * Vs[l4 + 1][lane]
               + pq.z * Vs[l4 + 2][lane] + pq.w * Vs[l4 + 3][lane];
        }
        __syncthreads();
    }
    y[(size_t)(b * Tt + t) * Cc + h * Dd + lane] = o / lrun;
}

// ---------------------------------------------------------------------------
// tpred: out[row] = dot(h[row], tp_w)   (one wave per row)
// ---------------------------------------------------------------------------
__global__ __launch_bounds__(256)
void tpred_kernel(const float* __restrict__ h, const float* __restrict__ tp,
                  float* __restrict__ out)
{
    const int row  = blockIdx.x * 4 + (threadIdx.x >> 6);
    const int lane = threadIdx.x & 63;
    const float* hr = h + (size_t)row * Cc;
    float s = 0.f;
#pragma unroll
    for (int j = 0; j < 12; ++j) s += hr[lane + (j << 6)] * tp[lane + (j << 6)];
#pragma unroll
    for (int m = 32; m; m >>= 1) s += __shfl_xor(s, m);
    if (lane == 0) out[row] = s;
}

// ---------------------------------------------------------------------------
extern "C" void kernel_launch(void* const* d_in, const int* in_sizes, int n_in,
                              void* d_out, int out_size, void* d_ws, size_t ws_size,
                              hipStream_t stream)
{
    const int*   idx  = (const int*)d_in[0];
    const float* ts   = (const float*)d_in[1];
    const float* wte  = (const float*)d_in[2];
    const float* freq = (const float*)d_in[3];
    const float* ph   = (const float*)d_in[4];
    const float* wpe  = (const float*)d_in[5];
    const float* ln1w = (const float*)d_in[6];
    const float* ln1b = (const float*)d_in[7];
    const float* qkvw = (const float*)d_in[8];
    const float* qkvb = (const float*)d_in[9];
    const float* pw   = (const float*)d_in[10];
    const float* pb   = (const float*)d_in[11];
    const float* ln2w = (const float*)d_in[12];
    const float* ln2b = (const float*)d_in[13];
    const float* fcw  = (const float*)d_in[14];
    const float* fcb  = (const float*)d_in[15];
    const float* f2w  = (const float*)d_in[16];
    const float* f2b  = (const float*)d_in[17];
    const float* lnfw = (const float*)d_in[18];
    const float* lnfb = (const float*)d_in[19];
    const float* lmw  = (const float*)d_in[20];
    const float* tpw  = (const float*)d_in[21];
    float* out = (float*)d_out;

    // workspace layout (all f32): ~126 MB
    float* x   = (float*)d_ws;                     // [4096, 768]
    float* h   = x   + (size_t)MTOT * Cc;          // [4096, 768]
    float* qkv = h   + (size_t)MTOT * Cc;          // [4096, 2304]
    float* y   = qkv + (size_t)MTOT * 3 * Cc;      // [4096, 768]
    float* mb  = y   + (size_t)MTOT * Cc;          // [4096, 3072]

    embed_kernel<<<MTOT, 256, 0, stream>>>(idx, ts, wte, freq, ph, wpe, x);

    for (int l = 0; l < Ll; ++l) {
        ln_kernel<<<MTOT, 256, 0, stream>>>(x, ln1w + l * Cc, ln1b + l * Cc, h);
        gemm_bt<0><<<dim3(64, 36), 256, 0, stream>>>(
            h, qkvw + (size_t)l * 3 * Cc * Cc, qkvb + (size_t)l * 3 * Cc,
            nullptr, qkv, 3 * Cc, Cc);
        attn_kernel<<<dim3(Tt / 4, Bb * Hh), 256, 0, stream>>>(qkv, y);
        gemm_bt<1><<<dim3(64, 12), 256, 0, stream>>>(
            y, pw + (size_t)l * Cc * Cc, pb + (size_t)l * Cc, x, x, Cc, Cc);
        ln_kernel<<<MTOT, 256, 0, stream>>>(x, ln2w + l * Cc, ln2b + l * Cc, h);
        gemm_bt<2><<<dim3(64, 48), 256, 0, stream>>>(
            h, fcw + (size_t)l * 4 * Cc * Cc, fcb + (size_t)l * 4 * Cc,
            nullptr, mb, 4 * Cc, Cc);
        gemm_bt<1><<<dim3(64, 12), 256, 0, stream>>>(
            mb, f2w + (size_t)l * Cc * 4 * Cc, f2b + (size_t)l * Cc, x, x, Cc, 4 * Cc);
    }

    ln_kernel<<<MTOT, 256, 0, stream>>>(x, lnfw, lnfb, h);
    gemm_bt<0><<<dim3(64, 157), 256, 0, stream>>>(
        h, lmw, nullptr, nullptr, out, Vv, Cc);
    tpred_kernel<<<MTOT / 4, 256, 0, stream>>>(h, tpw, out + (size_t)MTOT * Vv);
}

// Round 2
// 3753.136 us; speedup vs baseline: 2.5982x; 2.5982x over previous
//
#include <hip/hip_runtime.h>
#include <hip/hip_bf16.h>
#include <math.h>

#define Bb   4
#define Tt   1024
#define Cc   768
#define Hh   12
#define Dd   64
#define Ll   12
#define Vv   10000
#define WTEe 704
#define MTOT 4096   // B*T

typedef __bf16 bf16x8 __attribute__((ext_vector_type(8)));
typedef float  f32x4  __attribute__((ext_vector_type(4)));
typedef unsigned short u16;
typedef u16 u16x8 __attribute__((ext_vector_type(8)));

typedef const __attribute__((address_space(1))) void* gptr_t;
typedef __attribute__((address_space(3))) void* lptr_t;

__device__ inline void gload16(const void* g, void* l) {
    __builtin_amdgcn_global_load_lds((gptr_t)g, (lptr_t)l, 16, 0, 0);
}

__device__ inline u16 f2bf(float f) {
    unsigned int u = __float_as_uint(f);
    return (u16)((u + 0x7fffu + ((u >> 16) & 1u)) >> 16);   // RNE
}
__device__ inline float bf2f(u16 u) { return __uint_as_float(((unsigned)u) << 16); }

// ---------------------------------------------------------------------------
// float -> bf16 conversion (weights / one-shot)
// ---------------------------------------------------------------------------
__global__ __launch_bounds__(256)
void convert_bf16(const float* __restrict__ in, u16* __restrict__ out, int n4)
{
    int i = blockIdx.x * 256 + threadIdx.x;
    if (i >= n4) return;
    float4 v = ((const float4*)in)[i];
    ushort4 o;
    o.x = f2bf(v.x); o.y = f2bf(v.y); o.z = f2bf(v.z); o.w = f2bf(v.w);
    ((ushort4*)out)[i] = o;
}

// ---------------------------------------------------------------------------
// Embedding (f32 residual stream)
// ---------------------------------------------------------------------------
__global__ __launch_bounds__(256)
void embed_kernel(const int* __restrict__ idx, const float* __restrict__ ts,
                  const float* __restrict__ wte, const float* __restrict__ freq,
                  const float* __restrict__ ph, const float* __restrict__ wpe,
                  float* __restrict__ x)
{
    const int bt  = blockIdx.x;
    const int t   = bt & (Tt - 1);
    const int tok = idx[bt];
    const float tv = ts[bt];
#pragma unroll
    for (int j = 0; j < 3; ++j) {
        int c = threadIdx.x + (j << 8);
        float val;
        if (c < WTEe) val = wte[(size_t)tok * WTEe + c];
        else {
            int e = c - WTEe;
            val = cosf(tv * freq[e] + ph[e]);
        }
        x[(size_t)bt * Cc + c] = val + wpe[(size_t)t * Cc + c];
    }
}

// ---------------------------------------------------------------------------
// LayerNorm: f32 in -> bf16 out
// ---------------------------------------------------------------------------
__global__ __launch_bounds__(256)
void ln_kernel(const float* __restrict__ x, const float* __restrict__ wt,
               const float* __restrict__ bs, u16* __restrict__ out)
{
    const int row = blockIdx.x;
    const int tid = threadIdx.x;
    const float* xr = x + (size_t)row * Cc;
    float v0 = xr[tid], v1 = xr[tid + 256], v2 = xr[tid + 512];
    float s = v0 + v1 + v2;
#pragma unroll
    for (int m = 32; m; m >>= 1) s += __shfl_xor(s, m);
    __shared__ float red[4];
    const int wv = tid >> 6;
    if ((tid & 63) == 0) red[wv] = s;
    __syncthreads();
    float mu = (red[0] + red[1] + red[2] + red[3]) * (1.f / 768.f);
    float d0 = v0 - mu, d1 = v1 - mu, d2 = v2 - mu;
    float s2 = d0 * d0 + d1 * d1 + d2 * d2;
#pragma unroll
    for (int m = 32; m; m >>= 1) s2 += __shfl_xor(s2, m);
    __syncthreads();
    if ((tid & 63) == 0) red[wv] = s2;
    __syncthreads();
    float var = (red[0] + red[1] + red[2] + red[3]) * (1.f / 768.f);
    float rs = rsqrtf(var + 1e-5f);
    u16* orow = out + (size_t)row * Cc;
    orow[tid]       = f2bf(d0 * rs * wt[tid]       + bs[tid]);
    orow[tid + 256] = f2bf(d1 * rs * wt[tid + 256] + bs[tid + 256]);
    orow[tid + 512] = f2bf(d2 * rs * wt[tid + 512] + bs[tid + 512]);
}

// ---------------------------------------------------------------------------
// bf16 GEMM, m97 structure: BM=BN=128, BK=32, 4 waves, fragment-major LDS
// filled by global_load_lds(16B) with pre-swizzled per-lane source addresses.
// out[M,N] = A[M,K] @ W[N,K]^T (+bias) (+epilogue)
// EPI: 0 = bias, 1 = bias + f32 resid add, 2 = bias + exact GELU
// ---------------------------------------------------------------------------
__device__ inline void st_out(float* p, size_t o, float v) { p[o] = v; }
__device__ inline void st_out(u16*   p, size_t o, float v) { p[o] = f2bf(v); }

template<int EPI, typename OutT>
__global__ __launch_bounds__(256)
void gemm_bf16(const u16* __restrict__ A, const u16* __restrict__ W,
               const float* __restrict__ bias, const float* __restrict__ resid,
               OutT* __restrict__ out, int N, int K)
{
    __shared__ uint4 AF[8][64];
    __shared__ uint4 BF[8][64];
    const int tid  = threadIdx.x;
    const int lane = tid & 63;
    const int w    = tid >> 6;
    const int wr   = w >> 1, wc = w & 1;
    const int lq   = lane & 15, g = lane >> 4;
    const int m0   = blockIdx.x * 128, n0 = blockIdx.y * 128;

    const int arow0 = m0 + (2 * w) * 16 + lq;
    const int arow1 = arow0 + 16;
    int brow0 = n0 + (2 * w) * 16 + lq;
    int brow1 = brow0 + 16;
    brow0 = brow0 < N ? brow0 : N - 1;
    brow1 = brow1 < N ? brow1 : N - 1;
    const u16* ap0 = A + (size_t)arow0 * K + g * 8;
    const u16* ap1 = A + (size_t)arow1 * K + g * 8;
    const u16* bp0 = W + (size_t)brow0 * K + g * 8;
    const u16* bp1 = W + (size_t)brow1 * K + g * 8;

    f32x4 acc[4][4] = {};

    for (int k0 = 0; k0 < K; k0 += 32) {
        __syncthreads();                       // prev frag reads done
        gload16(ap0 + k0, &AF[2 * w][lane]);
        gload16(ap1 + k0, &AF[2 * w + 1][lane]);
        gload16(bp0 + k0, &BF[2 * w][lane]);
        gload16(bp1 + k0, &BF[2 * w + 1][lane]);
        __syncthreads();                       // vmcnt drained -> LDS ready

        bf16x8 af[4], bf[4];
#pragma unroll
        for (int mi = 0; mi < 4; ++mi)
            af[mi] = __builtin_bit_cast(bf16x8, AF[wr * 4 + mi][lane]);
#pragma unroll
        for (int ni = 0; ni < 4; ++ni)
            bf[ni] = __builtin_bit_cast(bf16x8, BF[wc * 4 + ni][lane]);
#pragma unroll
        for (int mi = 0; mi < 4; ++mi)
#pragma unroll
            for (int ni = 0; ni < 4; ++ni)
                acc[mi][ni] = __builtin_amdgcn_mfma_f32_16x16x32_bf16(
                    af[mi], bf[ni], acc[mi][ni], 0, 0, 0);
    }

#pragma unroll
    for (int mi = 0; mi < 4; ++mi)
#pragma unroll
        for (int ni = 0; ni < 4; ++ni) {
            int col = n0 + wc * 64 + ni * 16 + lq;
            if (col >= N) continue;
            int row = m0 + wr * 64 + mi * 16 + g * 4;
            float bv = bias ? bias[col] : 0.f;
#pragma unroll
            for (int q = 0; q < 4; ++q) {
                float v = acc[mi][ni][q] + bv;
                size_t o = (size_t)(row + q) * N + col;
                if (EPI == 1) v += resid[o];
                if (EPI == 2) v = 0.5f * v * (1.f + erff(v * 0.70710678118f));
                st_out(out, o, v);
            }
        }
}

// ---------------------------------------------------------------------------
// MFMA flash attention (bf16 qkv in, bf16 y out).
// Grid (T/64, B*H). 4 waves x 16 q-rows. KV chunks of 64 keys.
// K staged fragment-major via global_load_lds; V transposed to Vt[64][72];
// P via per-wave LDS round-trip; online softmax in registers.
// ---------------------------------------------------------------------------
__global__ __launch_bounds__(256)
void attn_mfma(const u16* __restrict__ qkv, u16* __restrict__ y)
{
    __shared__ uint4 KF[4][2][64];     // [nt][ks][lane] : K fragment tiles
    __shared__ u16  Vt[64][72];        // V^T, padded rows (144B)
    __shared__ u16  P4[4][16][72];     // per-wave P [q][key], padded

    const int tid  = threadIdx.x;
    const int lane = tid & 63;
    const int w    = tid >> 6;
    const int lq   = lane & 15, g = lane >> 4;
    const int qi   = blockIdx.x;
    const int bh   = blockIdx.y;
    const int b    = bh / Hh, h = bh % Hh;
    const int wq0  = qi * 64 + w * 16;
    const size_t base = (size_t)b * Tt * (3 * Cc);

    // Q fragments (2 k-slabs), held in registers
    const u16* qrow = qkv + base + (size_t)(wq0 + lq) * (3 * Cc) + h * Dd;
    bf16x8 qf0 = __builtin_bit_cast(bf16x8, *(const uint4*)(qrow + g * 8));
    bf16x8 qf1 = __builtin_bit_cast(bf16x8, *(const uint4*)(qrow + 32 + g * 8));

    f32x4 yac[4] = {};
    f32x4 mrun = { -1e30f, -1e30f, -1e30f, -1e30f };
    f32x4 lrun = { 0.f, 0.f, 0.f, 0.f };

    const int kr = tid >> 2, seg = tid & 3;

    for (int c = 0; c <= qi; ++c) {
        const int s0 = c * 64;
        __syncthreads();   // prev-chunk LDS reads done

        // K fragment staging: wave w stages tile nt=w, both k-slabs
        const u16* kp = qkv + base + (size_t)(s0 + w * 16 + lq) * (3 * Cc)
                        + Cc + h * Dd + g * 8;
        gload16(kp,      &KF[w][0][lane]);
        gload16(kp + 32, &KF[w][1][lane]);

        // V rows -> transposed Vt (bf16 scalar scatter)
        const u16* vp = qkv + base + (size_t)(s0 + kr) * (3 * Cc)
                        + 2 * Cc + h * Dd + seg * 16;
        uint4 v0 = *(const uint4*)vp;
        uint4 v1 = *(const uint4*)(vp + 8);
        u16x8 e0 = __builtin_bit_cast(u16x8, v0);
        u16x8 e1 = __builtin_bit_cast(u16x8, v1);
#pragma unroll
        for (int u = 0; u < 8; ++u) {
            Vt[seg * 16 + u][kr]     = e0[u];
            Vt[seg * 16 + 8 + u][kr] = e1[u];
        }
        __syncthreads();   // K gload drained + Vt visible

        // S = Q K^T  (16 q-rows x 64 keys per wave)
        f32x4 sc[4] = {};
#pragma unroll
        for (int nt = 0; nt < 4; ++nt) {
            bf16x8 k0 = __builtin_bit_cast(bf16x8, KF[nt][0][lane]);
            bf16x8 k1 = __builtin_bit_cast(bf16x8, KF[nt][1][lane]);
            sc[nt] = __builtin_amdgcn_mfma_f32_16x16x32_bf16(qf0, k0, sc[nt], 0, 0, 0);
            sc[nt] = __builtin_amdgcn_mfma_f32_16x16x32_bf16(qf1, k1, sc[nt], 0, 0, 0);
        }
#pragma unroll
        for (int nt = 0; nt < 4; ++nt) sc[nt] *= 0.125f;

        if (c == qi) {   // diagonal chunk: causal mask
#pragma unroll
            for (int nt = 0; nt < 4; ++nt)
#pragma unroll
                for (int j = 0; j < 4; ++j) {
                    int key = s0 + nt * 16 + lq;
                    int qr  = wq0 + g * 4 + j;
                    if (key > qr) sc[nt][j] = -1e30f;
                }
        }

        // online softmax (rows = g*4+j, reduce across 16 lanes of same g)
        f32x4 mx;
#pragma unroll
        for (int j = 0; j < 4; ++j)
            mx[j] = fmaxf(fmaxf(sc[0][j], sc[1][j]), fmaxf(sc[2][j], sc[3][j]));
#pragma unroll
        for (int msk = 1; msk < 16; msk <<= 1)
#pragma unroll
            for (int j = 0; j < 4; ++j)
                mx[j] = fmaxf(mx[j], __shfl_xor(mx[j], msk));

        f32x4 mnew, fac, ps = { 0.f, 0.f, 0.f, 0.f };
#pragma unroll
        for (int j = 0; j < 4; ++j) {
            mnew[j] = fmaxf(mrun[j], mx[j]);
            fac[j]  = __expf(mrun[j] - mnew[j]);
        }
#pragma unroll
        for (int nt = 0; nt < 4; ++nt)
#pragma unroll
            for (int j = 0; j < 4; ++j) {
                float p = __expf(sc[nt][j] - mnew[j]);
                sc[nt][j] = p;
                ps[j] += p;
            }
#pragma unroll
        for (int msk = 1; msk < 16; msk <<= 1)
#pragma unroll
            for (int j = 0; j < 4; ++j)
                ps[j] += __shfl_xor(ps[j], msk);
#pragma unroll
        for (int j = 0; j < 4; ++j) {
            lrun[j] = lrun[j] * fac[j] + ps[j];
            mrun[j] = mnew[j];
        }
#pragma unroll
        for (int dt = 0; dt < 4; ++dt) yac[dt] *= fac;

        // write P (bf16) to per-wave LDS
#pragma unroll
        for (int nt = 0; nt < 4; ++nt)
#pragma unroll
            for (int j = 0; j < 4; ++j)
                P4[w][g * 4 + j][nt * 16 + lq] = f2bf(sc[nt][j]);
        __syncthreads();   // P + Vt ordering before PV reads

        // PV: Y += P V
        bf16x8 pa0 = __builtin_bit_cast(bf16x8, *(const uint4*)&P4[w][lq][g * 8]);
        bf16x8 pa1 = __builtin_bit_cast(bf16x8, *(const uint4*)&P4[w][lq][32 + g * 8]);
#pragma unroll
        for (int dt = 0; dt < 4; ++dt) {
            bf16x8 vb0 = __builtin_bit_cast(bf16x8, *(const uint4*)&Vt[dt * 16 + lq][g * 8]);
            bf16x8 vb1 = __builtin_bit_cast(bf16x8, *(const uint4*)&Vt[dt * 16 + lq][32 + g * 8]);
            yac[dt] = __builtin_amdgcn_mfma_f32_16x16x32_bf16(pa0, vb0, yac[dt], 0, 0, 0);
            yac[dt] = __builtin_amdgcn_mfma_f32_16x16x32_bf16(pa1, vb1, yac[dt], 0, 0, 0);
        }
    }

    f32x4 rl;
#pragma unroll
    for (int j = 0; j < 4; ++j) rl[j] = 1.0f / lrun[j];
#pragma unroll
    for (int dt = 0; dt < 4; ++dt)
#pragma unroll
        for (int j = 0; j < 4; ++j)
            y[(size_t)(b * Tt + wq0 + g * 4 + j) * Cc + h * Dd + dt * 16 + lq]
                = f2bf(yac[dt][j] * rl[j]);
}

// ---------------------------------------------------------------------------
// tpred: out[row] = dot(h[row], tp_w)
// ---------------------------------------------------------------------------
__global__ __launch_bounds__(256)
void tpred_kernel(const u16* __restrict__ h, const float* __restrict__ tp,
                  float* __restrict__ out)
{
    const int row  = blockIdx.x * 4 + (threadIdx.x >> 6);
    const int lane = threadIdx.x & 63;
    const u16* hr = h + (size_t)row * Cc;
    float s = 0.f;
#pragma unroll
    for (int j = 0; j < 12; ++j) s += bf2f(hr[lane + (j << 6)]) * tp[lane + (j << 6)];
#pragma unroll
    for (int m = 32; m; m >>= 1) s += __shfl_xor(s, m);
    if (lane == 0) out[row] = s;
}

// ---------------------------------------------------------------------------
extern "C" void kernel_launch(void* const* d_in, const int* in_sizes, int n_in,
                              void* d_out, int out_size, void* d_ws, size_t ws_size,
                              hipStream_t stream)
{
    const int*   idx  = (const int*)d_in[0];
    const float* ts   = (const float*)d_in[1];
    const float* wte  = (const float*)d_in[2];
    const float* freq = (const float*)d_in[3];
    const float* ph   = (const float*)d_in[4];
    const float* wpe  = (const float*)d_in[5];
    const float* ln1w = (const float*)d_in[6];
    const float* ln1b = (const float*)d_in[7];
    const float* qkvw = (const float*)d_in[8];
    const float* qkvb = (const float*)d_in[9];
    const float* pw   = (const float*)d_in[10];
    const float* pb   = (const float*)d_in[11];
    const float* ln2w = (const float*)d_in[12];
    const float* ln2b = (const float*)d_in[13];
    const float* fcw  = (const float*)d_in[14];
    const float* fcb  = (const float*)d_in[15];
    const float* f2w  = (const float*)d_in[16];
    const float* f2b  = (const float*)d_in[17];
    const float* lnfw = (const float*)d_in[18];
    const float* lnfb = (const float*)d_in[19];
    const float* lmw  = (const float*)d_in[20];
    const float* tpw  = (const float*)d_in[21];
    float* out = (float*)d_out;

    // ---- workspace layout (~99 MB) ----
    char* p = (char*)d_ws;
    float* x    = (float*)p;               p += (size_t)MTOT * Cc * 4;       // f32 residual
    u16*   qkvB = (u16*)p;                 p += (size_t)MTOT * 3 * Cc * 2;
    u16*   hB   = (u16*)p;                 p += (size_t)MTOT * Cc * 2;
    u16*   yB   = (u16*)p;                 p += (size_t)MTOT * Cc * 2;
    u16*   mbB  = (u16*)p;                 p += (size_t)MTOT * 4 * Cc * 2;
    u16*   wqB  = (u16*)p;                 p += (size_t)3 * Cc * Cc * 2;     // per-layer qkv w
    u16*   wpB  = (u16*)p;                 p += (size_t)Cc * Cc * 2;
    u16*   wfB  = (u16*)p;                 p += (size_t)4 * Cc * Cc * 2;
    u16*   wf2B = (u16*)p;                 p += (size_t)Cc * 4 * Cc * 2;
    u16*   lmwB = (u16*)p;                 p += (size_t)Vv * Cc * 2;

    const int n_qkvw = 3 * Cc * Cc, n_pw = Cc * Cc, n_fcw = 4 * Cc * Cc;
    auto cvt = [&](const float* src, u16* dst, int n) {
        convert_bf16<<<(n / 4 + 255) / 256, 256, 0, stream>>>(src, dst, n / 4);
    };

    cvt(lmw, lmwB, Vv * Cc);
    embed_kernel<<<MTOT, 256, 0, stream>>>(idx, ts, wte, freq, ph, wpe, x);

    for (int l = 0; l < Ll; ++l) {
        cvt(qkvw + (size_t)l * n_qkvw, wqB, n_qkvw);
        cvt(pw   + (size_t)l * n_pw,   wpB, n_pw);
        cvt(fcw  + (size_t)l * n_fcw,  wfB, n_fcw);
        cvt(f2w  + (size_t)l * n_fcw,  wf2B, n_fcw);

        ln_kernel<<<MTOT, 256, 0, stream>>>(x, ln1w + l * Cc, ln1b + l * Cc, hB);
        gemm_bf16<0, u16><<<dim3(32, 18), 256, 0, stream>>>(
            hB, wqB, qkvb + (size_t)l * 3 * Cc, nullptr, qkvB, 3 * Cc, Cc);
        attn_mfma<<<dim3(Tt / 64, Bb * Hh), 256, 0, stream>>>(qkvB, yB);
        gemm_bf16<1, float><<<dim3(32, 6), 256, 0, stream>>>(
            yB, wpB, pb + (size_t)l * Cc, x, x, Cc, Cc);
        ln_kernel<<<MTOT, 256, 0, stream>>>(x, ln2w + l * Cc, ln2b + l * Cc, hB);
        gemm_bf16<2, u16><<<dim3(32, 24), 256, 0, stream>>>(
            hB, wfB, fcb + (size_t)l * 4 * Cc, nullptr, mbB, 4 * Cc, Cc);
        gemm_bf16<1, float><<<dim3(32, 6), 256, 0, stream>>>(
            mbB, wf2B, f2b + (size_t)l * Cc, x, x, Cc, 4 * Cc);
    }

    ln_kernel<<<MTOT, 256, 0, stream>>>(x, lnfw, lnfb, hB);
    gemm_bf16<0, float><<<dim3(32, 79), 256, 0, stream>>>(
        hB, lmwB, nullptr, nullptr, out, Vv, Cc);
    tpred_kernel<<<MTOT / 4, 256, 0, stream>>>(hB, tpw, out + (size_t)MTOT * Vv);
}

// Round 3
// 3558.078 us; speedup vs baseline: 2.7407x; 1.0548x over previous
//
#include <hip/hip_runtime.h>
#include <hip/hip_bf16.h>
#include <math.h>

#define Bb   4
#define Tt   1024
#define Cc   768
#define Hh   12
#define Dd   64
#define Ll   12
#define Vv   10000
#define WTEe 704
#define MTOT 4096   // B*T

typedef __bf16 bf16x8 __attribute__((ext_vector_type(8)));
typedef float  f32x4  __attribute__((ext_vector_type(4)));
typedef unsigned short u16;

typedef const __attribute__((address_space(1))) void* gptr_t;
typedef __attribute__((address_space(3))) void* lptr_t;

__device__ inline void gload16(const void* g, void* l) {
    __builtin_amdgcn_global_load_lds((gptr_t)g, (lptr_t)l, 16, 0, 0);
}

__device__ inline u16 f2bf(float f) {
    unsigned int u = __float_as_uint(f);
    return (u16)((u + 0x7fffu + ((u >> 16) & 1u)) >> 16);   // RNE
}
__device__ inline float bf2f(u16 u) { return __uint_as_float(((unsigned)u) << 16); }

// ---------------------------------------------------------------------------
// float -> bf16 conversion (weights)
// ---------------------------------------------------------------------------
__global__ __launch_bounds__(256)
void convert_bf16(const float* __restrict__ in, u16* __restrict__ out, int n4)
{
    int i = blockIdx.x * 256 + threadIdx.x;
    if (i >= n4) return;
    float4 v = ((const float4*)in)[i];
    ushort4 o;
    o.x = f2bf(v.x); o.y = f2bf(v.y); o.z = f2bf(v.z); o.w = f2bf(v.w);
    ((ushort4*)out)[i] = o;
}

// ---------------------------------------------------------------------------
// Embedding (f32 residual stream)
// ---------------------------------------------------------------------------
__global__ __launch_bounds__(256)
void embed_kernel(const int* __restrict__ idx, const float* __restrict__ ts,
                  const float* __restrict__ wte, const float* __restrict__ freq,
                  const float* __restrict__ ph, const float* __restrict__ wpe,
                  float* __restrict__ x)
{
    const int bt  = blockIdx.x;
    const int t   = bt & (Tt - 1);
    const int tok = idx[bt];
    const float tv = ts[bt];
#pragma unroll
    for (int j = 0; j < 3; ++j) {
        int c = threadIdx.x + (j << 8);
        float val;
        if (c < WTEe) val = wte[(size_t)tok * WTEe + c];
        else {
            int e = c - WTEe;
            val = cosf(tv * freq[e] + ph[e]);
        }
        x[(size_t)bt * Cc + c] = val + wpe[(size_t)t * Cc + c];
    }
}

// ---------------------------------------------------------------------------
// LayerNorm: f32 in -> bf16 out
// ---------------------------------------------------------------------------
__global__ __launch_bounds__(256)
void ln_kernel(const float* __restrict__ x, const float* __restrict__ wt,
               const float* __restrict__ bs, u16* __restrict__ out)
{
    const int row = blockIdx.x;
    const int tid = threadIdx.x;
    const float* xr = x + (size_t)row * Cc;
    float v0 = xr[tid], v1 = xr[tid + 256], v2 = xr[tid + 512];
    float s = v0 + v1 + v2;
#pragma unroll
    for (int m = 32; m; m >>= 1) s += __shfl_xor(s, m);
    __shared__ float red[4];
    const int wv = tid >> 6;
    if ((tid & 63) == 0) red[wv] = s;
    __syncthreads();
    float mu = (red[0] + red[1] + red[2] + red[3]) * (1.f / 768.f);
    float d0 = v0 - mu, d1 = v1 - mu, d2 = v2 - mu;
    float s2 = d0 * d0 + d1 * d1 + d2 * d2;
#pragma unroll
    for (int m = 32; m; m >>= 1) s2 += __shfl_xor(s2, m);
    __syncthreads();
    if ((tid & 63) == 0) red[wv] = s2;
    __syncthreads();
    float var = (red[0] + red[1] + red[2] + red[3]) * (1.f / 768.f);
    float rs = rsqrtf(var + 1e-5f);
    u16* orow = out + (size_t)row * Cc;
    orow[tid]       = f2bf(d0 * rs * wt[tid]       + bs[tid]);
    orow[tid + 256] = f2bf(d1 * rs * wt[tid + 256] + bs[tid + 256]);
    orow[tid + 512] = f2bf(d2 * rs * wt[tid + 512] + bs[tid + 512]);
}

// ---------------------------------------------------------------------------
// bf16 GEMM, 2-phase double-buffered (T3-minimal): BM=BN=128, BK=32, 4 waves.
// Stage tile t+1 BEFORE computing tile t; one __syncthreads per k-step.
// out[M,N] = A[M,K] @ W[N,K]^T (+bias) (+epilogue)
// EPI: 0 = bias, 1 = bias + f32 resid add, 2 = bias + exact GELU,
//      3 = qkv: cols<1536 normal bf16, cols>=1536 (V) -> transposed vt[b,h,d,T]
// ---------------------------------------------------------------------------
__device__ inline void st_out(float* p, size_t o, float v) { p[o] = v; }
__device__ inline void st_out(u16*   p, size_t o, float v) { p[o] = f2bf(v); }

template<int EPI, typename OutT>
__global__ __launch_bounds__(256)
void gemm_bf16(const u16* __restrict__ A, const u16* __restrict__ W,
               const float* __restrict__ bias, const float* __restrict__ resid,
               OutT* __restrict__ out, u16* __restrict__ vt, int N, int K)
{
    __shared__ uint4 AF[2][8][64];
    __shared__ uint4 BF[2][8][64];
    const int tid  = threadIdx.x;
    const int lane = tid & 63;
    const int w    = tid >> 6;
    const int wr   = w >> 1, wc = w & 1;
    const int lq   = lane & 15, g = lane >> 4;
    const int m0   = blockIdx.x * 128, n0 = blockIdx.y * 128;

    const int arow0 = m0 + (2 * w) * 16 + lq;
    const int arow1 = arow0 + 16;
    int brow0 = n0 + (2 * w) * 16 + lq;
    int brow1 = brow0 + 16;
    brow0 = brow0 < N ? brow0 : N - 1;
    brow1 = brow1 < N ? brow1 : N - 1;
    const u16* ap0 = A + (size_t)arow0 * K + g * 8;
    const u16* ap1 = A + (size_t)arow1 * K + g * 8;
    const u16* bp0 = W + (size_t)brow0 * K + g * 8;
    const u16* bp1 = W + (size_t)brow1 * K + g * 8;

    f32x4 acc[4][4] = {};

    const int nk = K >> 5;
    // prologue: stage tile 0 into buf 0
    gload16(ap0, &AF[0][2 * w][lane]);
    gload16(ap1, &AF[0][2 * w + 1][lane]);
    gload16(bp0, &BF[0][2 * w][lane]);
    gload16(bp1, &BF[0][2 * w + 1][lane]);
    __syncthreads();

    int buf = 0;
    for (int t = 0; t < nk; ++t) {
        if (t + 1 < nk) {                       // stage next while computing
            int k1 = (t + 1) << 5;
            gload16(ap0 + k1, &AF[buf ^ 1][2 * w][lane]);
            gload16(ap1 + k1, &AF[buf ^ 1][2 * w + 1][lane]);
            gload16(bp0 + k1, &BF[buf ^ 1][2 * w][lane]);
            gload16(bp1 + k1, &BF[buf ^ 1][2 * w + 1][lane]);
        }
        bf16x8 af[4], bfr[4];
#pragma unroll
        for (int mi = 0; mi < 4; ++mi)
            af[mi] = __builtin_bit_cast(bf16x8, AF[buf][wr * 4 + mi][lane]);
#pragma unroll
        for (int ni = 0; ni < 4; ++ni)
            bfr[ni] = __builtin_bit_cast(bf16x8, BF[buf][wc * 4 + ni][lane]);
#pragma unroll
        for (int mi = 0; mi < 4; ++mi)
#pragma unroll
            for (int ni = 0; ni < 4; ++ni)
                acc[mi][ni] = __builtin_amdgcn_mfma_f32_16x16x32_bf16(
                    af[mi], bfr[ni], acc[mi][ni], 0, 0, 0);
        __syncthreads();                        // drains vmcnt -> next buf ready
        buf ^= 1;
    }

    if (EPI == 3 && n0 >= 1536) {               // V block -> transposed vt
#pragma unroll
        for (int mi = 0; mi < 4; ++mi)
#pragma unroll
            for (int ni = 0; ni < 4; ++ni) {
                int col = n0 + wc * 64 + ni * 16 + lq;
                int c2  = col - 1536;
                int hh  = c2 >> 6, dd = c2 & 63;
                int row = m0 + wr * 64 + mi * 16 + g * 4;
                int bb  = row >> 10, tr = row & 1023;
                float bv = bias[col];
                ushort4 o;
                o.x = f2bf(acc[mi][ni][0] + bv);
                o.y = f2bf(acc[mi][ni][1] + bv);
                o.z = f2bf(acc[mi][ni][2] + bv);
                o.w = f2bf(acc[mi][ni][3] + bv);
                *(ushort4*)&vt[(((size_t)bb * Hh + hh) * Dd + dd) * Tt + tr] = o;
            }
        return;
    }

#pragma unroll
    for (int mi = 0; mi < 4; ++mi)
#pragma unroll
        for (int ni = 0; ni < 4; ++ni) {
            int col = n0 + wc * 64 + ni * 16 + lq;
            if (col >= N) continue;
            int row = m0 + wr * 64 + mi * 16 + g * 4;
            float bv = bias ? bias[col] : 0.f;
#pragma unroll
            for (int q = 0; q < 4; ++q) {
                float v = acc[mi][ni][q] + bv;
                size_t o = (size_t)(row + q) * N + col;
                if (EPI == 1) v += resid[o];
                if (EPI == 2) v = 0.5f * v * (1.f + erff(v * 0.70710678118f));
                st_out(out, o, v);
            }
        }
}

// ---------------------------------------------------------------------------
// MFMA flash attention. Q,K from qkv (bf16); V from pre-transposed vt[b,h,d,T].
// Grid (T/64, B*H), 4 waves x 16 q-rows. K/V double-buffered fragment-major
// LDS via global_load_lds; 2 barriers per 64-key chunk; online softmax in regs.
// ---------------------------------------------------------------------------
__global__ __launch_bounds__(256)
void attn_mfma(const u16* __restrict__ qkv, const u16* __restrict__ vt,
               u16* __restrict__ y)
{
    __shared__ uint4 KF[2][4][2][64];   // [buf][nt][kslab][lane]
    __shared__ uint4 VF[2][4][2][64];   // [buf][dt][sslab][lane]
    __shared__ u16  P4[4][16][72];      // per-wave P [q][key], padded

    const int tid  = threadIdx.x;
    const int lane = tid & 63;
    const int w    = tid >> 6;
    const int lq   = lane & 15, g = lane >> 4;
    const int qi   = blockIdx.x;
    const int bh   = blockIdx.y;
    const int b    = bh / Hh, h = bh % Hh;
    const int wq0  = qi * 64 + w * 16;
    const size_t base = (size_t)b * Tt * (3 * Cc);

    const u16* qrow = qkv + base + (size_t)(wq0 + lq) * (3 * Cc) + h * Dd;
    bf16x8 qf0 = __builtin_bit_cast(bf16x8, *(const uint4*)(qrow + g * 8));
    bf16x8 qf1 = __builtin_bit_cast(bf16x8, *(const uint4*)(qrow + 32 + g * 8));

    f32x4 yac[4] = {};
    f32x4 mrun = { -1e30f, -1e30f, -1e30f, -1e30f };
    f32x4 lrun = { 0.f, 0.f, 0.f, 0.f };

    const u16* kbase = qkv + base + Cc + h * Dd + (size_t)(w * 16 + lq) * (3 * Cc) + g * 8;
    const u16* vbase = vt + ((size_t)bh * Dd + w * 16 + lq) * Tt + g * 8;

#define STAGE(c, bi)  do {                                              \
        const u16* kp = kbase + (size_t)(c) * 64 * (3 * Cc);            \
        gload16(kp,      &KF[bi][w][0][lane]);                          \
        gload16(kp + 32, &KF[bi][w][1][lane]);                          \
        const u16* vp = vbase + (c) * 64;                               \
        gload16(vp,      &VF[bi][w][0][lane]);                          \
        gload16(vp + 32, &VF[bi][w][1][lane]);                          \
    } while (0)

    STAGE(0, 0);
    __syncthreads();

    int buf = 0;
    for (int c = 0; c <= qi; ++c) {
        if (c < qi) STAGE(c + 1, buf ^ 1);

        // S = Q K^T
        f32x4 sc[4] = {};
        __builtin_amdgcn_s_setprio(1);
#pragma unroll
        for (int nt = 0; nt < 4; ++nt) {
            bf16x8 k0 = __builtin_bit_cast(bf16x8, KF[buf][nt][0][lane]);
            bf16x8 k1 = __builtin_bit_cast(bf16x8, KF[buf][nt][1][lane]);
            sc[nt] = __builtin_amdgcn_mfma_f32_16x16x32_bf16(qf0, k0, sc[nt], 0, 0, 0);
            sc[nt] = __builtin_amdgcn_mfma_f32_16x16x32_bf16(qf1, k1, sc[nt], 0, 0, 0);
        }
        __builtin_amdgcn_s_setprio(0);
#pragma unroll
        for (int nt = 0; nt < 4; ++nt) sc[nt] *= 0.125f;

        if (c == qi) {   // diagonal chunk: causal mask
            const int s0 = c * 64;
#pragma unroll
            for (int nt = 0; nt < 4; ++nt)
#pragma unroll
                for (int j = 0; j < 4; ++j) {
                    int key = s0 + nt * 16 + lq;
                    int qr  = wq0 + g * 4 + j;
                    if (key > qr) sc[nt][j] = -1e30f;
                }
        }

        // online softmax (rows = g*4+j, reduce across 16 lanes sharing g)
        f32x4 mx;
#pragma unroll
        for (int j = 0; j < 4; ++j)
            mx[j] = fmaxf(fmaxf(sc[0][j], sc[1][j]), fmaxf(sc[2][j], sc[3][j]));
#pragma unroll
        for (int msk = 1; msk < 16; msk <<= 1)
#pragma unroll
            for (int j = 0; j < 4; ++j)
                mx[j] = fmaxf(mx[j], __shfl_xor(mx[j], msk));

        f32x4 mnew, fac, ps = { 0.f, 0.f, 0.f, 0.f };
#pragma unroll
        for (int j = 0; j < 4; ++j) {
            mnew[j] = fmaxf(mrun[j], mx[j]);
            fac[j]  = __expf(mrun[j] - mnew[j]);
        }
#pragma unroll
        for (int nt = 0; nt < 4; ++nt)
#pragma unroll
            for (int j = 0; j < 4; ++j) {
                float p = __expf(sc[nt][j] - mnew[j]);
                sc[nt][j] = p;
                ps[j] += p;
            }
#pragma unroll
        for (int msk = 1; msk < 16; msk <<= 1)
#pragma unroll
            for (int j = 0; j < 4; ++j)
                ps[j] += __shfl_xor(ps[j], msk);
#pragma unroll
        for (int j = 0; j < 4; ++j) {
            lrun[j] = lrun[j] * fac[j] + ps[j];
            mrun[j] = mnew[j];
        }
#pragma unroll
        for (int dt = 0; dt < 4; ++dt) yac[dt] *= fac;

#pragma unroll
        for (int nt = 0; nt < 4; ++nt)
#pragma unroll
            for (int j = 0; j < 4; ++j)
                P4[w][g * 4 + j][nt * 16 + lq] = f2bf(sc[nt][j]);
        __syncthreads();   // P4 visible; staged c+1 K/V landed

        // PV: Y += P V   (B-frags from pre-transposed V, vector reads)
        bf16x8 pa0 = __builtin_bit_cast(bf16x8, *(const uint4*)&P4[w][lq][g * 8]);
        bf16x8 pa1 = __builtin_bit_cast(bf16x8, *(const uint4*)&P4[w][lq][32 + g * 8]);
        __builtin_amdgcn_s_setprio(1);
#pragma unroll
        for (int dt = 0; dt < 4; ++dt) {
            bf16x8 vb0 = __builtin_bit_cast(bf16x8, VF[buf][dt][0][lane]);
            bf16x8 vb1 = __builtin_bit_cast(bf16x8, VF[buf][dt][1][lane]);
            yac[dt] = __builtin_amdgcn_mfma_f32_16x16x32_bf16(pa0, vb0, yac[dt], 0, 0, 0);
            yac[dt] = __builtin_amdgcn_mfma_f32_16x16x32_bf16(pa1, vb1, yac[dt], 0, 0, 0);
        }
        __builtin_amdgcn_s_setprio(0);
        __syncthreads();   // retire P4/KF/VF reads before next-iter writes
        buf ^= 1;
    }
#undef STAGE

    f32x4 rl;
#pragma unroll
    for (int j = 0; j < 4; ++j) rl[j] = 1.0f / lrun[j];
#pragma unroll
    for (int dt = 0; dt < 4; ++dt)
#pragma unroll
        for (int j = 0; j < 4; ++j)
            y[(size_t)(b * Tt + wq0 + g * 4 + j) * Cc + h * Dd + dt * 16 + lq]
                = f2bf(yac[dt][j] * rl[j]);
}

// ---------------------------------------------------------------------------
// tpred: out[row] = dot(h[row], tp_w)
// ---------------------------------------------------------------------------
__global__ __launch_bounds__(256)
void tpred_kernel(const u16* __restrict__ h, const float* __restrict__ tp,
                  float* __restrict__ out)
{
    const int row  = blockIdx.x * 4 + (threadIdx.x >> 6);
    const int lane = threadIdx.x & 63;
    const u16* hr = h + (size_t)row * Cc;
    float s = 0.f;
#pragma unroll
    for (int j = 0; j < 12; ++j) s += bf2f(hr[lane + (j << 6)]) * tp[lane + (j << 6)];
#pragma unroll
    for (int m = 32; m; m >>= 1) s += __shfl_xor(s, m);
    if (lane == 0) out[row] = s;
}

// ---------------------------------------------------------------------------
extern "C" void kernel_launch(void* const* d_in, const int* in_sizes, int n_in,
                              void* d_out, int out_size, void* d_ws, size_t ws_size,
                              hipStream_t stream)
{
    const int*   idx  = (const int*)d_in[0];
    const float* ts   = (const float*)d_in[1];
    const float* wte  = (const float*)d_in[2];
    const float* freq = (const float*)d_in[3];
    const float* ph   = (const float*)d_in[4];
    const float* wpe  = (const float*)d_in[5];
    const float* ln1w = (const float*)d_in[6];
    const float* ln1b = (const float*)d_in[7];
    const float* qkvw = (const float*)d_in[8];
    const float* qkvb = (const float*)d_in[9];
    const float* pw   = (const float*)d_in[10];
    const float* pb   = (const float*)d_in[11];
    const float* ln2w = (const float*)d_in[12];
    const float* ln2b = (const float*)d_in[13];
    const float* fcw  = (const float*)d_in[14];
    const float* fcb  = (const float*)d_in[15];
    const float* f2w  = (const float*)d_in[16];
    const float* f2b  = (const float*)d_in[17];
    const float* lnfw = (const float*)d_in[18];
    const float* lnfb = (const float*)d_in[19];
    const float* lmw  = (const float*)d_in[20];
    const float* tpw  = (const float*)d_in[21];
    float* out = (float*)d_out;

    // ---- workspace layout (~105 MB) ----
    char* p = (char*)d_ws;
    float* x    = (float*)p;               p += (size_t)MTOT * Cc * 4;
    u16*   qkvB = (u16*)p;                 p += (size_t)MTOT * 3 * Cc * 2;
    u16*   VtB  = (u16*)p;                 p += (size_t)Bb * Hh * Dd * Tt * 2;
    u16*   hB   = (u16*)p;                 p += (size_t)MTOT * Cc * 2;
    u16*   yB   = (u16*)p;                 p += (size_t)MTOT * Cc * 2;
    u16*   mbB  = (u16*)p;                 p += (size_t)MTOT * 4 * Cc * 2;
    u16*   wqB  = (u16*)p;                 p += (size_t)3 * Cc * Cc * 2;
    u16*   wpB  = (u16*)p;                 p += (size_t)Cc * Cc * 2;
    u16*   wfB  = (u16*)p;                 p += (size_t)4 * Cc * Cc * 2;
    u16*   wf2B = (u16*)p;                 p += (size_t)Cc * 4 * Cc * 2;
    u16*   lmwB = (u16*)p;                 p += (size_t)Vv * Cc * 2;

    const int n_qkvw = 3 * Cc * Cc, n_pw = Cc * Cc, n_fcw = 4 * Cc * Cc;
    auto cvt = [&](const float* src, u16* dst, int n) {
        convert_bf16<<<(n / 4 + 255) / 256, 256, 0, stream>>>(src, dst, n / 4);
    };

    cvt(lmw, lmwB, Vv * Cc);
    embed_kernel<<<MTOT, 256, 0, stream>>>(idx, ts, wte, freq, ph, wpe, x);

    for (int l = 0; l < Ll; ++l) {
        cvt(qkvw + (size_t)l * n_qkvw, wqB, n_qkvw);
        cvt(pw   + (size_t)l * n_pw,   wpB, n_pw);
        cvt(fcw  + (size_t)l * n_fcw,  wfB, n_fcw);
        cvt(f2w  + (size_t)l * n_fcw,  wf2B, n_fcw);

        ln_kernel<<<MTOT, 256, 0, stream>>>(x, ln1w + l * Cc, ln1b + l * Cc, hB);
        gemm_bf16<3, u16><<<dim3(32, 18), 256, 0, stream>>>(
            hB, wqB, qkvb + (size_t)l * 3 * Cc, nullptr, qkvB, VtB, 3 * Cc, Cc);
        attn_mfma<<<dim3(Tt / 64, Bb * Hh), 256, 0, stream>>>(qkvB, VtB, yB);
        gemm_bf16<1, float><<<dim3(32, 6), 256, 0, stream>>>(
            yB, wpB, pb + (size_t)l * Cc, x, x, nullptr, Cc, Cc);
        ln_kernel<<<MTOT, 256, 0, stream>>>(x, ln2w + l * Cc, ln2b + l * Cc, hB);
        gemm_bf16<2, u16><<<dim3(32, 24), 256, 0, stream>>>(
            hB, wfB, fcb + (size_t)l * 4 * Cc, nullptr, mbB, nullptr, 4 * Cc, Cc);
        gemm_bf16<1, float><<<dim3(32, 6), 256, 0, stream>>>(
            mbB, wf2B, f2b + (size_t)l * Cc, x, x, nullptr, Cc, 4 * Cc);
    }

    ln_kernel<<<MTOT, 256, 0, stream>>>(x, lnfw, lnfb, hB);
    gemm_bf16<0, float><<<dim3(32, 79), 256, 0, stream>>>(
        hB, lmwB, nullptr, nullptr, out, nullptr, Vv, Cc);
    tpred_kernel<<<MTOT / 4, 256, 0, stream>>>(hB, tpw, out + (size_t)MTOT * Vv);
}